// Round 5
// baseline (119.250 us; speedup 1.0000x reference)
//
#include <hip/hip_runtime.h>
#include <math.h>

#define BATCH 4
#define SEQ   1024
#define HID   512
#define NHEAD 8

typedef unsigned short u16;
typedef unsigned int   u32;
typedef short  short8 __attribute__((ext_vector_type(8)));
typedef float  f32x4  __attribute__((ext_vector_type(4)));

__device__ __forceinline__ u16 f2bf(float x) {
  u32 u = __builtin_bit_cast(u32, x);
  u32 r = (u + 0x7FFFu + ((u >> 16) & 1u)) >> 16;
  return (u16)r;
}
__device__ __forceinline__ float bf2f(u16 h) {
  u32 u = ((u32)h) << 16;
  return __builtin_bit_cast(float, u);
}

// ---------------- fp32 -> bf16 convert: x (524288 float4s) then pe (262016) --
__global__ __launch_bounds__(256)
void cvt_two(const float* __restrict__ x, const float* __restrict__ pe,
             u16* __restrict__ xb, u16* __restrict__ peb) {
  int i = blockIdx.x * 256 + threadIdx.x;
  const float* s;
  u16* d;
  if (i < 524288) {
    s = x; d = xb;
  } else {
    i -= 524288;
    if (i >= 262016) return;
    s = pe; d = peb;
  }
  float4 v = *(const float4*)&s[(size_t)i * 4];
  ushort4 o;
  o.x = f2bf(v.x); o.y = f2bf(v.y); o.z = f2bf(v.z); o.w = f2bf(v.w);
  *(ushort4*)&d[(size_t)i * 4] = o;
}

// ---------------- W (512x512 f32 k-major) -> Wt (n-major bf16), 5 mats -------
__global__ __launch_bounds__(256)
void transpose_w(const float* w0, const float* w1, const float* w2,
                 const float* w3, const float* w4, u16* __restrict__ wt) {
  const float* src;
  switch (blockIdx.z) {
    case 0: src = w0; break;
    case 1: src = w1; break;
    case 2: src = w2; break;
    case 3: src = w3; break;
    default: src = w4; break;
  }
  u16* dst = wt + (size_t)blockIdx.z * 512 * 512;
  __shared__ float t[32][33];
  const int tx = threadIdx.x, ty = threadIdx.y;  // block (32,8)
  const int k0 = blockIdx.x * 32, n0 = blockIdx.y * 32;
#pragma unroll
  for (int r = 0; r < 4; ++r)
    t[ty + 8 * r][tx] = src[(size_t)(k0 + ty + 8 * r) * 512 + n0 + tx];
  __syncthreads();
#pragma unroll
  for (int r = 0; r < 4; ++r)
    dst[(size_t)(n0 + ty + 8 * r) * 512 + k0 + tx] = f2bf(t[tx][ty + 8 * r]);
}

// ---------------- MFMA GEMM core: acc = A[BMx512] @ Bt^T tile ---------------
// MF=4 -> BM=128; MF=2 -> BM=64. BN=128, BK=64. 4 waves (2x2).
template <int MF>
__device__ __forceinline__ void gemm_core(const u16* __restrict__ A,
                                          const u16* __restrict__ Bt,
                                          int m0, int n0, u16* As, u16* Bs,
                                          f32x4 (&acc)[MF][4]) {
  const int tid = threadIdx.x;
  const int wid = tid >> 6, lane = tid & 63;
  const int lr = lane & 15, lg = lane >> 4;
  const int wm = wid >> 1, wn = wid & 1;
  const int srow = tid >> 3, sc = tid & 7;
#pragma unroll
  for (int i = 0; i < MF; ++i)
#pragma unroll
    for (int j = 0; j < 4; ++j) acc[i][j] = (f32x4)0.f;

  for (int kt = 0; kt < 8; ++kt) {
    const int k0 = kt * 64;
    short8 la[MF], lb[4];
#pragma unroll
    for (int r = 0; r < MF; ++r)
      la[r] = *(const short8*)&A[(size_t)(m0 + srow + 32 * r) * 512 + k0 + sc * 8];
#pragma unroll
    for (int r = 0; r < 4; ++r)
      lb[r] = *(const short8*)&Bt[(size_t)(n0 + srow + 32 * r) * 512 + k0 + sc * 8];
    __syncthreads();
#pragma unroll
    for (int r = 0; r < MF; ++r) {
      int row = srow + 32 * r;
      *(short8*)&As[row * 64 + ((sc ^ (row & 7)) * 8)] = la[r];
    }
#pragma unroll
    for (int r = 0; r < 4; ++r) {
      int row = srow + 32 * r;
      *(short8*)&Bs[row * 64 + ((sc ^ (row & 7)) * 8)] = lb[r];
    }
    __syncthreads();
#pragma unroll
    for (int kc = 0; kc < 2; ++kc) {
      const int ch = kc * 4 + lg;
      short8 af[MF], bfr[4];
#pragma unroll
      for (int mt = 0; mt < MF; ++mt) {
        int row = wm * (MF * 16) + mt * 16 + lr;
        af[mt] = *(const short8*)&As[row * 64 + ((ch ^ (row & 7)) * 8)];
      }
#pragma unroll
      for (int nt = 0; nt < 4; ++nt) {
        int row = wn * 64 + nt * 16 + lr;
        bfr[nt] = *(const short8*)&Bs[row * 64 + ((ch ^ (row & 7)) * 8)];
      }
#pragma unroll
      for (int mt = 0; mt < MF; ++mt)
#pragma unroll
        for (int nt = 0; nt < 4; ++nt)
          acc[mt][nt] = __builtin_amdgcn_mfma_f32_16x16x32_bf16(
              af[mt], bfr[nt], acc[mt][nt], 0, 0, 0);
    }
  }
}

// ---------------- fused Q/K/V/P projection GEMM (z = 0..3) ------------------
__global__ __launch_bounds__(256)
void gemm_qkvp(const u16* __restrict__ xbf, const u16* __restrict__ pebf,
               const u16* __restrict__ wt,
               const float* __restrict__ bq, const float* __restrict__ bk,
               const float* __restrict__ bv, const float* __restrict__ bp,
               const float* __restrict__ pbu, const float* __restrict__ pbv,
               u16* __restrict__ qu, u16* __restrict__ qv,
               u16* __restrict__ kk, u16* __restrict__ vt,
               u16* __restrict__ pp) {
  __shared__ __align__(16) u16 As[128 * 64];
  __shared__ __align__(16) u16 Bs[128 * 64];
  const int z = blockIdx.z;
  if (z == 3 && blockIdx.y >= 16) return;
  const u16* A = (z == 3) ? pebf : xbf;
  const u16* Bt = wt + (size_t)z * 512 * 512;
  const float* bias = (z == 0) ? bq : (z == 1) ? bk : (z == 2) ? bv : bp;
  const int m0 = blockIdx.y * 128, n0 = blockIdx.x * 128;

  f32x4 acc[4][4];
  gemm_core<4>(A, Bt, m0, n0, As, Bs, acc);

  const int tid = threadIdx.x, wid = tid >> 6, lane = tid & 63;
  const int lr = lane & 15, lg = lane >> 4, wm = wid >> 1, wn = wid & 1;
#pragma unroll
  for (int mt = 0; mt < 4; ++mt)
#pragma unroll
    for (int nt = 0; nt < 4; ++nt) {
      const int col = n0 + wn * 64 + nt * 16 + lr;
      const int rb = m0 + wm * 64 + mt * 16 + lg * 4;
      const float bcol = bias[col];
      if (z == 0) {
        const float uu = pbu[col], vv = pbv[col];
#pragma unroll
        for (int q = 0; q < 4; ++q) {
          float val = acc[mt][nt][q] + bcol;
          qu[(size_t)(rb + q) * 512 + col] = f2bf(val + uu);
          qv[(size_t)(rb + q) * 512 + col] = f2bf(val + vv);
        }
      } else if (z == 1) {
#pragma unroll
        for (int q = 0; q < 4; ++q)
          kk[(size_t)(rb + q) * 512 + col] = f2bf(acc[mt][nt][q] + bcol);
      } else if (z == 2) {
        // V^T layout [b][h][d][t]
        ushort4 pk;
        pk.x = f2bf(acc[mt][nt][0] + bcol);
        pk.y = f2bf(acc[mt][nt][1] + bcol);
        pk.z = f2bf(acc[mt][nt][2] + bcol);
        pk.w = f2bf(acc[mt][nt][3] + bcol);
        int bb = rb >> 10, tl = rb & 1023;
        *(ushort4*)&vt[(size_t)((bb * 8 + (col >> 6)) * 64 + (col & 63)) * 1024 + tl] = pk;
      } else {
#pragma unroll
        for (int q = 0; q < 4; ++q)
          if (rb + q < 2047)
            pp[(size_t)(rb + q) * 512 + col] = f2bf(acc[mt][nt][q] + bcol);
      }
    }
}

// ---------------- output projection: out = ao @ Wo^T + bo (f32) -------------
__global__ __launch_bounds__(256)
void gemm_wo(const u16* __restrict__ ao, const u16* __restrict__ wt,
             const float* __restrict__ bo, float* __restrict__ out) {
  __shared__ __align__(16) u16 As[64 * 64];
  __shared__ __align__(16) u16 Bs[128 * 64];
  const int m0 = blockIdx.y * 64, n0 = blockIdx.x * 128;
  f32x4 acc[2][4];
  gemm_core<2>(ao, wt + (size_t)4 * 512 * 512, m0, n0, As, Bs, acc);
  const int tid = threadIdx.x, wid = tid >> 6, lane = tid & 63;
  const int lr = lane & 15, lg = lane >> 4, wm = wid >> 1, wn = wid & 1;
#pragma unroll
  for (int mt = 0; mt < 2; ++mt)
#pragma unroll
    for (int nt = 0; nt < 4; ++nt) {
      const int col = n0 + wn * 64 + nt * 16 + lr;
      const int rb = m0 + wm * 32 + mt * 16 + lg * 4;
      const float bcol = bo[col];
#pragma unroll
      for (int q = 0; q < 4; ++q)
        out[(size_t)(rb + q) * 512 + col] = acc[mt][nt][q] + bcol;
    }
}

// ---------------- flash rel-pos attention, bf16 MFMA, j-split x2 -------------
// grid (16, NHEAD, BATCH*2): z -> (b, half). Each block: 64 q-rows over 512 j.
// Writes unnormalized O partials + (m,l) per row; combine kernel merges.
__global__ __launch_bounds__(256)
void attn_mfma(const u16* __restrict__ quP, const u16* __restrict__ qvP,
               const u16* __restrict__ kP, const u16* __restrict__ vtP,
               const u16* __restrict__ pP, float* __restrict__ opart,
               float* __restrict__ mlbuf) {
  __shared__ __align__(16) u16 Ks[64 * 64];     // [j][d] swz
  __shared__ __align__(16) u16 Vs[64 * 64];     // [d][j] swz (V^T tile)
  __shared__ __align__(16) u16 Ps[128 * 64];    // [r][d] swz
  __shared__ __align__(16) u16 Es[4][16 * 64];  // per-wave exp(S) bf16, swz

  const int tid = threadIdx.x;
  const int wid = tid >> 6, lane = tid & 63;
  const int lr = lane & 15, lg = lane >> 4;
  const int srow = tid >> 3, sc = tid & 7;
  const int t0 = blockIdx.x * 64, h = blockIdx.y;
  const int b = blockIdx.z >> 1, half = blockIdx.z & 1;
  const int jlo = half << 9;

  short8 aqu[2], aqv[2];
#pragma unroll
  for (int kc = 0; kc < 2; ++kc) {
    size_t g = (size_t)(b * SEQ + t0 + wid * 16 + lr) * 512 + h * 64 + kc * 32 + lg * 8;
    aqu[kc] = *(const short8*)&quP[g];
    aqv[kc] = *(const short8*)&qvP[g];
  }

  float mrun[4] = {-1e30f, -1e30f, -1e30f, -1e30f};
  float lrun[4] = {0.f, 0.f, 0.f, 0.f};
  f32x4 cO[4];
#pragma unroll
  for (int i = 0; i < 4; ++i) cO[i] = (f32x4)0.f;

  u16* esw = &Es[wid][0];

  for (int j0 = jlo; j0 < jlo + 512; j0 += 64) {
    const int base = 960 - t0 + j0;  // window start, >=0, +127 <= 2047
    short8 lk[2], lv[2], lp[4];
#pragma unroll
    for (int r = 0; r < 2; ++r) {
      int row = srow + 32 * r;
      lk[r] = *(const short8*)&kP[(size_t)(b * SEQ + j0 + row) * 512 + h * 64 + sc * 8];
      lv[r] = *(const short8*)&vtP[(size_t)((b * 8 + h) * 64 + row) * 1024 + j0 + sc * 8];
    }
#pragma unroll
    for (int r = 0; r < 4; ++r) {
      int row = srow + 32 * r;
      lp[r] = *(const short8*)&pP[(size_t)(base + row) * 512 + h * 64 + sc * 8];
    }
    __syncthreads();  // previous tile's reads done before overwrite
#pragma unroll
    for (int r = 0; r < 2; ++r) {
      int row = srow + 32 * r;
      *(short8*)&Ks[row * 64 + ((sc ^ (row & 7)) * 8)] = lk[r];
      *(short8*)&Vs[row * 64 + ((sc ^ (row & 7)) * 8)] = lv[r];
    }
#pragma unroll
    for (int r = 0; r < 4; ++r) {
      int row = srow + 32 * r;
      *(short8*)&Ps[row * 64 + ((sc ^ (row & 7)) * 8)] = lp[r];
    }
    __syncthreads();

    // ---- S_K = Qu @ K^T ; windowed Bd = Qv @ P^T ----
    f32x4 cK[4], cP5[5];
#pragma unroll
    for (int i = 0; i < 4; ++i) cK[i] = (f32x4)0.f;
#pragma unroll
    for (int i = 0; i < 5; ++i) cP5[i] = (f32x4)0.f;
    __builtin_amdgcn_s_setprio(1);
#pragma unroll
    for (int kc = 0; kc < 2; ++kc) {
      const int ch = kc * 4 + lg;
#pragma unroll
      for (int nt = 0; nt < 4; ++nt) {
        int row = nt * 16 + lr;
        short8 bk = *(const short8*)&Ks[row * 64 + ((ch ^ (row & 7)) * 8)];
        cK[nt] = __builtin_amdgcn_mfma_f32_16x16x32_bf16(aqu[kc], bk, cK[nt], 0, 0, 0);
      }
#pragma unroll
      for (int pt = 0; pt < 5; ++pt) {
        int row = (3 - wid + pt) * 16 + lr;
        short8 bp = *(const short8*)&Ps[row * 64 + ((ch ^ (row & 7)) * 8)];
        cP5[pt] = __builtin_amdgcn_mfma_f32_16x16x32_bf16(aqv[kc], bp, cP5[pt], 0, 0, 0);
      }
    }
    __builtin_amdgcn_s_setprio(0);

    // ---- rel-shift gather via shuffle: row m needs window col nt*16 + u, u = lr+15-m
    float s[4][4];
#pragma unroll
    for (int q = 0; q < 4; ++q) {
      int u = lr + 15 - lg * 4 - q;            // 0..30
      int src = (lane & 48) | (u & 15);
      float sh[5];
#pragma unroll
      for (int pt = 0; pt < 5; ++pt) sh[pt] = __shfl(cP5[pt][q], src, 64);
      bool hi = (u & 16) != 0;
#pragma unroll
      for (int nt = 0; nt < 4; ++nt) {
        float bd = hi ? sh[nt + 1] : sh[nt];
        s[nt][q] = 0.125f * (cK[nt][q] + bd);
      }
    }

    // ---- online softmax with defer-max (THR=8) ----
    float pm[4];
#pragma unroll
    for (int q = 0; q < 4; ++q) {
      float tm = fmaxf(fmaxf(s[0][q], s[1][q]), fmaxf(s[2][q], s[3][q]));
      tm = fmaxf(tm, __shfl_xor(tm, 1));
      tm = fmaxf(tm, __shfl_xor(tm, 2));
      tm = fmaxf(tm, __shfl_xor(tm, 4));
      tm = fmaxf(tm, __shfl_xor(tm, 8));
      pm[q] = tm;
    }
    int need = 0;
#pragma unroll
    for (int q = 0; q < 4; ++q) need |= (pm[q] > mrun[q] + 8.f) ? 1 : 0;
    if (__any(need)) {
#pragma unroll
      for (int q = 0; q < 4; ++q) {
        float mnew = fmaxf(mrun[q], pm[q]);
        float corr = __expf(mrun[q] - mnew);
        lrun[q] *= corr;
        mrun[q] = mnew;
#pragma unroll
        for (int nt = 0; nt < 4; ++nt) cO[nt][q] *= corr;
      }
    }

    // ---- exp -> bf16, store Es, accumulate quantized row sums ----
    float ps[4] = {0.f, 0.f, 0.f, 0.f};
#pragma unroll
    for (int nt = 0; nt < 4; ++nt) {
      int jp = nt * 16 + lr, sw = jp >> 3, jb = jp & 7;
#pragma unroll
      for (int q = 0; q < 4; ++q) {
        int m = lg * 4 + q;
        u16 eh = f2bf(__expf(s[nt][q] - mrun[q]));
        ps[q] += bf2f(eh);
        esw[m * 64 + ((sw ^ (m & 7)) * 8) + jb] = eh;
      }
    }
#pragma unroll
    for (int q = 0; q < 4; ++q) {
      float v = ps[q];
      v += __shfl_xor(v, 1);
      v += __shfl_xor(v, 2);
      v += __shfl_xor(v, 4);
      v += __shfl_xor(v, 8);
      lrun[q] += v;
    }

    // ---- O += E @ V ----
    __builtin_amdgcn_s_setprio(1);
#pragma unroll
    for (int kc = 0; kc < 2; ++kc) {
      const int ch = kc * 4 + lg;
      short8 ae = *(const short8*)&esw[lr * 64 + ((ch ^ (lr & 7)) * 8)];
#pragma unroll
      for (int nt = 0; nt < 4; ++nt) {
        int vr = nt * 16 + lr;
        short8 bv = *(const short8*)&Vs[vr * 64 + ((ch ^ (vr & 7)) * 8)];
        cO[nt] = __builtin_amdgcn_mfma_f32_16x16x32_bf16(ae, bv, cO[nt], 0, 0, 0);
      }
    }
    __builtin_amdgcn_s_setprio(0);
    __syncthreads();
  }

  // ---- write partials: O (unnormalized, f32), and (m, l) per row ----
  const size_t OH = (size_t)32768 * 64;  // per-half O elements
  const int rowbase = (b * 8 + h) * 1024 + t0 + wid * 16;
#pragma unroll
  for (int nt = 0; nt < 4; ++nt)
#pragma unroll
    for (int q = 0; q < 4; ++q) {
      int row = rowbase + lg * 4 + q;
      opart[half * OH + (size_t)row * 64 + nt * 16 + lr] = cO[nt][q];
    }
  if (lr == 0) {
#pragma unroll
    for (int q = 0; q < 4; ++q) {
      int row = rowbase + lg * 4 + q;
      mlbuf[half * 65536 + row * 2 + 0] = mrun[q];
      mlbuf[half * 65536 + row * 2 + 1] = lrun[q];
    }
  }
}

// ---------------- merge the two j-halves -> ao (bf16) ------------------------
__global__ __launch_bounds__(256)
void attn_combine(const float* __restrict__ opart, const float* __restrict__ mlbuf,
                  u16* __restrict__ ao) {
  const int wid = threadIdx.x >> 6, lane = threadIdx.x & 63;
  const int row = blockIdx.x * 4 + wid;  // (b*8+h)*1024 + t, 0..32767
  const int b = row >> 13, h = (row >> 10) & 7, t = row & 1023;
  const size_t OH = (size_t)32768 * 64;
  float o0 = opart[(size_t)row * 64 + lane];
  float o1 = opart[OH + (size_t)row * 64 + lane];
  float m0 = mlbuf[row * 2], l0 = mlbuf[row * 2 + 1];
  float m1 = mlbuf[65536 + row * 2], l1 = mlbuf[65536 + row * 2 + 1];
  float m = fmaxf(m0, m1);
  float w0 = __expf(m0 - m), w1 = __expf(m1 - m);
  float inv = 1.f / (w0 * l0 + w1 * l1);
  float val = (w0 * o0 + w1 * o1) * inv;
  ao[((size_t)(b * 1024 + t)) * 512 + h * 64 + lane] = f2bf(val);
}

extern "C" void kernel_launch(void* const* d_in, const int* in_sizes, int n_in,
                              void* d_out, int out_size, void* d_ws, size_t ws_size,
                              hipStream_t stream) {
  const float* x   = (const float*)d_in[0];
  const float* pe  = (const float*)d_in[1];
  const float* Wq  = (const float*)d_in[2];
  const float* bq  = (const float*)d_in[3];
  const float* Wk  = (const float*)d_in[4];
  const float* bk  = (const float*)d_in[5];
  const float* Wv  = (const float*)d_in[6];
  const float* bv  = (const float*)d_in[7];
  const float* Wp  = (const float*)d_in[8];
  const float* bp  = (const float*)d_in[9];
  const float* Wo  = (const float*)d_in[10];
  const float* bo  = (const float*)d_in[11];
  const float* pbu = (const float*)d_in[12];
  const float* pbv = (const float*)d_in[13];

  char* ws = (char*)d_ws;
  size_t o = 0;
  auto alloc = [&](size_t bytes) { size_t r = o; o += (bytes + 255) & ~(size_t)255; return r; };
  u16* x_bf  = (u16*)(ws + alloc((size_t)4096 * 512 * 2));
  u16* pe_bf = (u16*)(ws + alloc((size_t)2048 * 512 * 2));
  u16* wt    = (u16*)(ws + alloc((size_t)5 * 512 * 512 * 2));
  u16* qu    = (u16*)(ws + alloc((size_t)4096 * 512 * 2));
  u16* qv    = (u16*)(ws + alloc((size_t)4096 * 512 * 2));
  u16* kk    = (u16*)(ws + alloc((size_t)4096 * 512 * 2));
  u16* vt    = (u16*)(ws + alloc((size_t)4096 * 512 * 2));
  u16* pp    = (u16*)(ws + alloc((size_t)2048 * 512 * 2));
  u16* ao    = (u16*)(ws + alloc((size_t)4096 * 512 * 2));
  float* opart = (float*)(ws + alloc((size_t)2 * 32768 * 64 * 4));
  float* mlbuf = (float*)(ws + alloc((size_t)2 * 32768 * 2 * 4));

  dim3 blk(256);
  cvt_two<<<dim3(3072), blk, 0, stream>>>(x, pe, x_bf, pe_bf);
  transpose_w<<<dim3(16, 16, 5), dim3(32, 8), 0, stream>>>(Wq, Wk, Wv, Wp, Wo, wt);
  hipMemsetAsync(pp + (size_t)2047 * 512, 0, 512 * 2, stream);

  gemm_qkvp<<<dim3(4, 32, 4), blk, 0, stream>>>(x_bf, pe_bf, wt, bq, bk, bv, bp,
                                                pbu, pbv, qu, qv, kk, vt, pp);
  attn_mfma<<<dim3(16, NHEAD, BATCH * 2), blk, 0, stream>>>(qu, qv, kk, vt, pp,
                                                            opart, mlbuf);
  attn_combine<<<dim3(8192), blk, 0, stream>>>(opart, mlbuf, ao);
  gemm_wo<<<dim3(4, 64), blk, 0, stream>>>(ao, wt, bo, (float*)d_out);
}

// Round 6
// 86.161 us; speedup vs baseline: 1.3840x; 1.3840x over previous
//
#include <hip/hip_runtime.h>
#include <math.h>

#define BATCH 4
#define SEQ   1024
#define HID   512
#define NHEAD 8

typedef unsigned short u16;
typedef unsigned int   u32;
typedef short  short8 __attribute__((ext_vector_type(8)));
typedef float  f32x4  __attribute__((ext_vector_type(4)));

__device__ __forceinline__ u16 f2bf(float x) {
  u32 u = __builtin_bit_cast(u32, x);
  u32 r = (u + 0x7FFFu + ((u >> 16) & 1u)) >> 16;
  return (u16)r;
}
__device__ __forceinline__ float bf2f(u16 h) {
  u32 u = ((u32)h) << 16;
  return __builtin_bit_cast(float, u);
}

// max-reduce over the 16 lanes of a row via DPP (VALU only, no DS ops)
#define DPPMAX(x, ctrl)                                                        \
  x = fmaxf(x, __builtin_bit_cast(float, __builtin_amdgcn_update_dpp(          \
                   0, __builtin_bit_cast(int, x), ctrl, 0xf, 0xf, true)))

// ---------------- fp32 -> bf16 convert: x (524288 float4s) then pe (262016) --
__global__ __launch_bounds__(256)
void cvt_two(const float* __restrict__ x, const float* __restrict__ pe,
             u16* __restrict__ xb, u16* __restrict__ peb) {
  int i = blockIdx.x * 256 + threadIdx.x;
  const float* s;
  u16* d;
  if (i < 524288) {
    s = x; d = xb;
  } else {
    i -= 524288;
    if (i >= 262016) return;
    s = pe; d = peb;
  }
  float4 v = *(const float4*)&s[(size_t)i * 4];
  ushort4 o;
  o.x = f2bf(v.x); o.y = f2bf(v.y); o.z = f2bf(v.z); o.w = f2bf(v.w);
  *(ushort4*)&d[(size_t)i * 4] = o;
}

// ---------------- W (512x512 f32 k-major) -> Wt (n-major bf16), 5 mats -------
__global__ __launch_bounds__(256)
void transpose_w(const float* w0, const float* w1, const float* w2,
                 const float* w3, const float* w4, u16* __restrict__ wt) {
  const float* src;
  switch (blockIdx.z) {
    case 0: src = w0; break;
    case 1: src = w1; break;
    case 2: src = w2; break;
    case 3: src = w3; break;
    default: src = w4; break;
  }
  u16* dst = wt + (size_t)blockIdx.z * 512 * 512;
  __shared__ float t[32][33];
  const int tx = threadIdx.x, ty = threadIdx.y;  // block (32,8)
  const int k0 = blockIdx.x * 32, n0 = blockIdx.y * 32;
#pragma unroll
  for (int r = 0; r < 4; ++r)
    t[ty + 8 * r][tx] = src[(size_t)(k0 + ty + 8 * r) * 512 + n0 + tx];
  __syncthreads();
#pragma unroll
  for (int r = 0; r < 4; ++r)
    dst[(size_t)(n0 + ty + 8 * r) * 512 + k0 + tx] = f2bf(t[tx][ty + 8 * r]);
}

// ---------------- MFMA GEMM core: acc = A[BMx512] @ Bt^T tile ---------------
// BM = MF*32, BN = NF*32. 4 waves (2x2). Register-staged + XOR-swizzled LDS.
template <int MF, int NF>
__device__ __forceinline__ void gemm_core(const u16* __restrict__ A,
                                          const u16* __restrict__ Bt,
                                          int m0, int n0, u16* As, u16* Bs,
                                          f32x4 (&acc)[MF][NF]) {
  const int tid = threadIdx.x;
  const int wid = tid >> 6, lane = tid & 63;
  const int lr = lane & 15, lg = lane >> 4;
  const int wm = wid >> 1, wn = wid & 1;
  const int srow = tid >> 3, sc = tid & 7;
#pragma unroll
  for (int i = 0; i < MF; ++i)
#pragma unroll
    for (int j = 0; j < NF; ++j) acc[i][j] = (f32x4)0.f;

  for (int kt = 0; kt < 8; ++kt) {
    const int k0 = kt * 64;
    short8 la[MF], lb[NF];
#pragma unroll
    for (int r = 0; r < MF; ++r)
      la[r] = *(const short8*)&A[(size_t)(m0 + srow + 32 * r) * 512 + k0 + sc * 8];
#pragma unroll
    for (int r = 0; r < NF; ++r)
      lb[r] = *(const short8*)&Bt[(size_t)(n0 + srow + 32 * r) * 512 + k0 + sc * 8];
    __syncthreads();
#pragma unroll
    for (int r = 0; r < MF; ++r) {
      int row = srow + 32 * r;
      *(short8*)&As[row * 64 + ((sc ^ (row & 7)) * 8)] = la[r];
    }
#pragma unroll
    for (int r = 0; r < NF; ++r) {
      int row = srow + 32 * r;
      *(short8*)&Bs[row * 64 + ((sc ^ (row & 7)) * 8)] = lb[r];
    }
    __syncthreads();
#pragma unroll
    for (int kc = 0; kc < 2; ++kc) {
      const int ch = kc * 4 + lg;
      short8 af[MF], bfr[NF];
#pragma unroll
      for (int mt = 0; mt < MF; ++mt) {
        int row = wm * (MF * 16) + mt * 16 + lr;
        af[mt] = *(const short8*)&As[row * 64 + ((ch ^ (row & 7)) * 8)];
      }
#pragma unroll
      for (int nt = 0; nt < NF; ++nt) {
        int row = wn * (NF * 16) + nt * 16 + lr;
        bfr[nt] = *(const short8*)&Bs[row * 64 + ((ch ^ (row & 7)) * 8)];
      }
#pragma unroll
      for (int mt = 0; mt < MF; ++mt)
#pragma unroll
        for (int nt = 0; nt < NF; ++nt)
          acc[mt][nt] = __builtin_amdgcn_mfma_f32_16x16x32_bf16(
              af[mt], bfr[nt], acc[mt][nt], 0, 0, 0);
    }
  }
}

// ---------------- fused Q/K/V/P projection GEMM (z = 0..3) ------------------
__global__ __launch_bounds__(256)
void gemm_qkvp(const u16* __restrict__ xbf, const u16* __restrict__ pebf,
               const u16* __restrict__ wt,
               const float* __restrict__ bq, const float* __restrict__ bk,
               const float* __restrict__ bv, const float* __restrict__ bp,
               const float* __restrict__ pbu, const float* __restrict__ pbv,
               u16* __restrict__ qu, u16* __restrict__ qv,
               u16* __restrict__ kk, u16* __restrict__ vt,
               u16* __restrict__ pp) {
  __shared__ __align__(16) u16 As[128 * 64];
  __shared__ __align__(16) u16 Bs[128 * 64];
  const int z = blockIdx.z;
  if (z == 3 && blockIdx.y >= 16) return;
  const u16* A = (z == 3) ? pebf : xbf;
  const u16* Bt = wt + (size_t)z * 512 * 512;
  const float* bias = (z == 0) ? bq : (z == 1) ? bk : (z == 2) ? bv : bp;
  const int m0 = blockIdx.y * 128, n0 = blockIdx.x * 128;

  f32x4 acc[4][4];
  gemm_core<4, 4>(A, Bt, m0, n0, As, Bs, acc);

  const int tid = threadIdx.x, wid = tid >> 6, lane = tid & 63;
  const int lr = lane & 15, lg = lane >> 4, wm = wid >> 1, wn = wid & 1;
#pragma unroll
  for (int mt = 0; mt < 4; ++mt)
#pragma unroll
    for (int nt = 0; nt < 4; ++nt) {
      const int col = n0 + wn * 64 + nt * 16 + lr;
      const int rb = m0 + wm * 64 + mt * 16 + lg * 4;
      const float bcol = bias[col];
      if (z == 0) {
        const float uu = pbu[col], vv = pbv[col];
#pragma unroll
        for (int q = 0; q < 4; ++q) {
          float val = acc[mt][nt][q] + bcol;
          qu[(size_t)(rb + q) * 512 + col] = f2bf(val + uu);
          qv[(size_t)(rb + q) * 512 + col] = f2bf(val + vv);
        }
      } else if (z == 1) {
#pragma unroll
        for (int q = 0; q < 4; ++q)
          kk[(size_t)(rb + q) * 512 + col] = f2bf(acc[mt][nt][q] + bcol);
      } else if (z == 2) {
        // V^T layout [b][h][d][t]
        ushort4 pk;
        pk.x = f2bf(acc[mt][nt][0] + bcol);
        pk.y = f2bf(acc[mt][nt][1] + bcol);
        pk.z = f2bf(acc[mt][nt][2] + bcol);
        pk.w = f2bf(acc[mt][nt][3] + bcol);
        int bb = rb >> 10, tl = rb & 1023;
        *(ushort4*)&vt[(size_t)((bb * 8 + (col >> 6)) * 64 + (col & 63)) * 1024 + tl] = pk;
      } else {
#pragma unroll
        for (int q = 0; q < 4; ++q)
          if (rb + q < 2047)
            pp[(size_t)(rb + q) * 512 + col] = f2bf(acc[mt][nt][q] + bcol);
      }
    }
}

// ---------------- output projection: out = ao @ Wo^T + bo (f32) -------------
// BM=64, BN=64 -> 512 blocks (2/CU).
__global__ __launch_bounds__(256)
void gemm_wo(const u16* __restrict__ ao, const u16* __restrict__ wt,
             const float* __restrict__ bo, float* __restrict__ out) {
  __shared__ __align__(16) u16 As[64 * 64];
  __shared__ __align__(16) u16 Bs[64 * 64];
  const int m0 = blockIdx.y * 64, n0 = blockIdx.x * 64;
  f32x4 acc[2][2];
  gemm_core<2, 2>(ao, wt + (size_t)4 * 512 * 512, m0, n0, As, Bs, acc);
  const int tid = threadIdx.x, wid = tid >> 6, lane = tid & 63;
  const int lr = lane & 15, lg = lane >> 4, wm = wid >> 1, wn = wid & 1;
#pragma unroll
  for (int mt = 0; mt < 2; ++mt)
#pragma unroll
    for (int nt = 0; nt < 2; ++nt) {
      const int col = n0 + wn * 32 + nt * 16 + lr;
      const int rb = m0 + wm * 32 + mt * 16 + lg * 4;
      const float bcol = bo[col];
#pragma unroll
      for (int q = 0; q < 4; ++q)
        out[(size_t)(rb + q) * 512 + col] = acc[mt][nt][q] + bcol;
    }
}

// ---------------- flash rel-pos attention, bf16 MFMA -------------------------
// block: (b, h, 64 q-rows). 4 waves, wave w owns rows t0+16w..+15.
// scores[t][j] = 0.125*(qu[t].k[j] + qv[t].p[1023-t+j]); online softmax; O=attn@V.
__global__ __launch_bounds__(256)
void attn_mfma(const u16* __restrict__ quP, const u16* __restrict__ qvP,
               const u16* __restrict__ kP, const u16* __restrict__ vtP,
               const u16* __restrict__ pP, u16* __restrict__ ao) {
  __shared__ __align__(16) u16 Ks[64 * 64];      // [j][d] swz
  __shared__ __align__(16) u16 Vs[64 * 64];      // [d][j] swz (V^T tile)
  __shared__ __align__(16) u16 Ps[128 * 64];     // [r][d] swz
  __shared__ __align__(16) u16 Es[4][16 * 64];   // per-wave exp(S) bf16, swz
  __shared__ float Bds[4][16][84];               // per-wave windowed Qv.P^T
                                                 // pad 84: write & read both 2-way (free)

  const int tid = threadIdx.x;
  const int wid = tid >> 6, lane = tid & 63;
  const int lr = lane & 15, lg = lane >> 4;
  const int srow = tid >> 3, sc = tid & 7;
  const int t0 = blockIdx.x * 64, h = blockIdx.y, b = blockIdx.z;

  short8 aqu[2], aqv[2];
#pragma unroll
  for (int kc = 0; kc < 2; ++kc) {
    size_t g = (size_t)(b * SEQ + t0 + wid * 16 + lr) * 512 + h * 64 + kc * 32 + lg * 8;
    aqu[kc] = *(const short8*)&quP[g];
    aqv[kc] = *(const short8*)&qvP[g];
  }
  short8 ones;
#pragma unroll
  for (int i = 0; i < 8; ++i) ones[i] = (short)0x3F80;  // bf16 1.0

  float mrun[4] = {-1e30f, -1e30f, -1e30f, -1e30f};
  f32x4 cL = (f32x4)0.f;  // running row-sums (denominator), rescaled with cO
  f32x4 cO[4];
#pragma unroll
  for (int i = 0; i < 4; ++i) cO[i] = (f32x4)0.f;

  u16* esw = &Es[wid][0];

  for (int j0 = 0; j0 < SEQ; j0 += 64) {
    const int base = 960 - t0 + j0;  // window start, >=0, +127 <= 2047
    short8 lk[2], lv[2], lp[4];
#pragma unroll
    for (int r = 0; r < 2; ++r) {
      int row = srow + 32 * r;
      lk[r] = *(const short8*)&kP[(size_t)(b * SEQ + j0 + row) * 512 + h * 64 + sc * 8];
      lv[r] = *(const short8*)&vtP[(size_t)((b * 8 + h) * 64 + row) * 1024 + j0 + sc * 8];
    }
#pragma unroll
    for (int r = 0; r < 4; ++r) {
      int row = srow + 32 * r;
      lp[r] = *(const short8*)&pP[(size_t)(base + row) * 512 + h * 64 + sc * 8];
    }
    __syncthreads();  // previous tile's reads done before overwrite
#pragma unroll
    for (int r = 0; r < 2; ++r) {
      int row = srow + 32 * r;
      *(short8*)&Ks[row * 64 + ((sc ^ (row & 7)) * 8)] = lk[r];
      *(short8*)&Vs[row * 64 + ((sc ^ (row & 7)) * 8)] = lv[r];
    }
#pragma unroll
    for (int r = 0; r < 4; ++r) {
      int row = srow + 32 * r;
      *(short8*)&Ps[row * 64 + ((sc ^ (row & 7)) * 8)] = lp[r];
    }
    __syncthreads();

    // ---- S_K = Qu @ K^T ; windowed Bd = Qv @ P^T ----
    f32x4 cK[4], cP5[5];
#pragma unroll
    for (int i = 0; i < 4; ++i) cK[i] = (f32x4)0.f;
#pragma unroll
    for (int i = 0; i < 5; ++i) cP5[i] = (f32x4)0.f;
    __builtin_amdgcn_s_setprio(1);
#pragma unroll
    for (int kc = 0; kc < 2; ++kc) {
      const int ch = kc * 4 + lg;
#pragma unroll
      for (int nt = 0; nt < 4; ++nt) {
        int row = nt * 16 + lr;
        short8 bk = *(const short8*)&Ks[row * 64 + ((ch ^ (row & 7)) * 8)];
        cK[nt] = __builtin_amdgcn_mfma_f32_16x16x32_bf16(aqu[kc], bk, cK[nt], 0, 0, 0);
      }
#pragma unroll
      for (int pt = 0; pt < 5; ++pt) {
        int row = (3 - wid + pt) * 16 + lr;
        short8 bp = *(const short8*)&Ps[row * 64 + ((ch ^ (row & 7)) * 8)];
        cP5[pt] = __builtin_amdgcn_mfma_f32_16x16x32_bf16(aqv[kc], bp, cP5[pt], 0, 0, 0);
      }
    }
    __builtin_amdgcn_s_setprio(0);

    // ---- rel-shift via per-wave LDS round-trip (conflict-free padding) ----
#pragma unroll
    for (int pt = 0; pt < 5; ++pt)
#pragma unroll
      for (int q = 0; q < 4; ++q)
        Bds[wid][lg * 4 + q][pt * 16 + lr] = cP5[pt][q];
    // same-wave write->read: program order + lgkmcnt (compiler) suffices
    float s[4][4];
#pragma unroll
    for (int q = 0; q < 4; ++q) {
      const int m = lg * 4 + q;
#pragma unroll
      for (int nt = 0; nt < 4; ++nt)
        s[nt][q] = 0.125f * (cK[nt][q] + Bds[wid][m][15 - m + nt * 16 + lr]);
    }

    // ---- online softmax with defer-max (THR=8); max-reduce via DPP ----
    float pm[4];
#pragma unroll
    for (int q = 0; q < 4; ++q) {
      float tm = fmaxf(fmaxf(s[0][q], s[1][q]), fmaxf(s[2][q], s[3][q]));
      DPPMAX(tm, 0xB1);   // quad_perm xor1
      DPPMAX(tm, 0x4E);   // quad_perm xor2
      DPPMAX(tm, 0x141);  // row_half_mirror
      DPPMAX(tm, 0x140);  // row_mirror
      pm[q] = tm;
    }
    int need = 0;
#pragma unroll
    for (int q = 0; q < 4; ++q) need |= (pm[q] > mrun[q] + 8.f) ? 1 : 0;
    if (__any(need)) {
#pragma unroll
      for (int q = 0; q < 4; ++q) {
        float mnew = fmaxf(mrun[q], pm[q]);
        float corr = __expf(mrun[q] - mnew);
        mrun[q] = mnew;
        cL[q] *= corr;
#pragma unroll
        for (int nt = 0; nt < 4; ++nt) cO[nt][q] *= corr;
      }
    }

    // ---- exp -> bf16, store Es ----
#pragma unroll
    for (int nt = 0; nt < 4; ++nt) {
      int jp = nt * 16 + lr, sw = jp >> 3, jb = jp & 7;
#pragma unroll
      for (int q = 0; q < 4; ++q) {
        int m = lg * 4 + q;
        esw[m * 64 + ((sw ^ (m & 7)) * 8) + jb] = f2bf(__expf(s[nt][q] - mrun[q]));
      }
    }

    // ---- O += E @ V ; rowsum += E @ ones (denominator via MFMA) ----
    __builtin_amdgcn_s_setprio(1);
#pragma unroll
    for (int kc = 0; kc < 2; ++kc) {
      const int ch = kc * 4 + lg;
      short8 ae = *(const short8*)&esw[lr * 64 + ((ch ^ (lr & 7)) * 8)];
      cL = __builtin_amdgcn_mfma_f32_16x16x32_bf16(ae, ones, cL, 0, 0, 0);
#pragma unroll
      for (int nt = 0; nt < 4; ++nt) {
        int vr = nt * 16 + lr;
        short8 bv = *(const short8*)&Vs[vr * 64 + ((ch ^ (vr & 7)) * 8)];
        cO[nt] = __builtin_amdgcn_mfma_f32_16x16x32_bf16(ae, bv, cO[nt], 0, 0, 0);
      }
    }
    __builtin_amdgcn_s_setprio(0);
    __syncthreads();
  }

  float inv[4];
#pragma unroll
  for (int q = 0; q < 4; ++q) inv[q] = 1.f / cL[q];
#pragma unroll
  for (int nt = 0; nt < 4; ++nt)
#pragma unroll
    for (int q = 0; q < 4; ++q) {
      int row = b * SEQ + t0 + wid * 16 + lg * 4 + q;
      ao[(size_t)row * 512 + h * 64 + nt * 16 + lr] = f2bf(cO[nt][q] * inv[q]);
    }
}

extern "C" void kernel_launch(void* const* d_in, const int* in_sizes, int n_in,
                              void* d_out, int out_size, void* d_ws, size_t ws_size,
                              hipStream_t stream) {
  const float* x   = (const float*)d_in[0];
  const float* pe  = (const float*)d_in[1];
  const float* Wq  = (const float*)d_in[2];
  const float* bq  = (const float*)d_in[3];
  const float* Wk  = (const float*)d_in[4];
  const float* bk  = (const float*)d_in[5];
  const float* Wv  = (const float*)d_in[6];
  const float* bv  = (const float*)d_in[7];
  const float* Wp  = (const float*)d_in[8];
  const float* bp  = (const float*)d_in[9];
  const float* Wo  = (const float*)d_in[10];
  const float* bo  = (const float*)d_in[11];
  const float* pbu = (const float*)d_in[12];
  const float* pbv = (const float*)d_in[13];

  char* ws = (char*)d_ws;
  size_t o = 0;
  auto alloc = [&](size_t bytes) { size_t r = o; o += (bytes + 255) & ~(size_t)255; return r; };
  u16* x_bf  = (u16*)(ws + alloc((size_t)4096 * 512 * 2));
  u16* pe_bf = (u16*)(ws + alloc((size_t)2048 * 512 * 2));
  u16* wt    = (u16*)(ws + alloc((size_t)5 * 512 * 512 * 2));
  u16* qu    = (u16*)(ws + alloc((size_t)4096 * 512 * 2));
  u16* qv    = (u16*)(ws + alloc((size_t)4096 * 512 * 2));
  u16* kk    = (u16*)(ws + alloc((size_t)4096 * 512 * 2));
  u16* vt    = (u16*)(ws + alloc((size_t)4096 * 512 * 2));
  u16* pp    = (u16*)(ws + alloc((size_t)2048 * 512 * 2));
  u16* ao    = (u16*)(ws + alloc((size_t)4096 * 512 * 2));

  dim3 blk(256);
  cvt_two<<<dim3(3072), blk, 0, stream>>>(x, pe, x_bf, pe_bf);
  transpose_w<<<dim3(16, 16, 5), dim3(32, 8), 0, stream>>>(Wq, Wk, Wv, Wp, Wo, wt);
  hipMemsetAsync(pp + (size_t)2047 * 512, 0, 512 * 2, stream);

  gemm_qkvp<<<dim3(4, 32, 4), blk, 0, stream>>>(x_bf, pe_bf, wt, bq, bk, bv, bp,
                                                pbu, pbv, qu, qv, kk, vt, pp);
  attn_mfma<<<dim3(16, NHEAD, BATCH), blk, 0, stream>>>(qu, qv, kk, vt, pp, ao);
  gemm_wo<<<dim3(8, 64), blk, 0, stream>>>(ao, wt, bo, (float*)d_out);
}